// Round 16
// baseline (96.738 us; speedup 1.0000x reference)
//
#include <hip/hip_runtime.h>
#include <hip/hip_bf16.h>
#include <math.h>

#define NB   2
#define NS   2048
#define NEMB 1024
#define NH   16
#define NHD  64

typedef __attribute__((ext_vector_type(8))) short short8;
typedef __attribute__((ext_vector_type(4))) float floatx4;

static __device__ __forceinline__ float bf2f(ushort u) {
    union { uint u; float f; } x; x.u = ((uint)u) << 16;
    return x.f;
}
// HW packed convert: dword = [bf16(lo) | bf16(hi)<<16]
static __device__ __forceinline__ uint cvt_pk(float lo, float hi) {
    uint r;
    asm("v_cvt_pk_bf16_f32 %0, %1, %2" : "=v"(r) : "v"(lo), "v"(hi));
    return r;
}
// async global->LDS, 16B/lane; LDS dest = wave-uniform base + lane*16
static __device__ __forceinline__ void gload16(const void* g, void* s) {
    __builtin_amdgcn_global_load_lds(
        (const __attribute__((address_space(1))) void*)g,
        (__attribute__((address_space(3))) void*)s, 16, 0, 0);
}

#define SWZ(row, bytecol) (((row) * 128 + (bytecol)) ^ (((row) & 7) << 4))

// ---------------------------------------------------------------------------
// Kernel 0: cast ALL weights fp32 -> bf16 (Wq,Wk,Wv: 64K elems each; Wo: 1M).
// ---------------------------------------------------------------------------
__global__ __launch_bounds__(256) void w_cast(
    const float* __restrict__ Wq, const float* __restrict__ Wk,
    const float* __restrict__ Wv, const float* __restrict__ Wo,
    ushort* __restrict__ Wqb, ushort* __restrict__ Wkb,
    ushort* __restrict__ Wvb, ushort* __restrict__ Wob)
{
    int i = (blockIdx.x * 256 + threadIdx.x) * 8;
    const float* src;
    ushort* dst;
    int off;
    if (i < 196608) {                    // 3 x 65536 (= NH*NHD*NHD)
        int sel = i >> 16;
        off = i & 65535;
        src = sel == 0 ? Wq : (sel == 1 ? Wk : Wv);
        dst = sel == 0 ? Wqb : (sel == 1 ? Wkb : Wvb);
    } else {
        off = i - 196608;
        src = Wo;
        dst = Wob;
    }
    float4 a = *(const float4*)&src[off];
    float4 b = *(const float4*)&src[off + 4];
    short8 o;
    ((uint*)&o)[0] = cvt_pk(a.x, a.y);
    ((uint*)&o)[1] = cvt_pk(a.z, a.w);
    ((uint*)&o)[2] = cvt_pk(b.x, b.y);
    ((uint*)&o)[3] = cvt_pk(b.z, b.w);
    *(short8*)&dst[off] = o;
}

// ---------------------------------------------------------------------------
// Kernel 1: fused QKV projection via MFMA (fp32 X/Z, bf16 weights, bf16 out),
// emits Q, K and TRANSPOSED V (Vt[b,h,d,s]). grid = (S/128, B*H), block 256.
// ---------------------------------------------------------------------------
__global__ __launch_bounds__(256) void qkv_mfma(
    const float* __restrict__ X, const float* __restrict__ Z,
    const ushort* __restrict__ Wqb, const float* __restrict__ bq,
    const ushort* __restrict__ Wkb, const float* __restrict__ bk,
    const ushort* __restrict__ Wvb, const float* __restrict__ bv,
    ushort* __restrict__ Q, ushort* __restrict__ K, ushort* __restrict__ Vt)
{
    int st = blockIdx.x, bh = blockIdx.y;
    int h = bh & (NH - 1), b = bh >> 4;
    int s0 = st * 128;

    __shared__ __align__(16) ushort xs[128 * 72];
    __shared__ __align__(16) ushort zs[128 * 72];
    __shared__ __align__(16) ushort wqs[64 * 64], wks[64 * 64], wvs[64 * 64];

    int t = threadIdx.x, w = t >> 6, l = t & 63;
    int l16 = l & 15, lg = l >> 4;

#pragma unroll
    for (int c = 0; c < 4; ++c) {
        int chunk = c * 256 + t;
        int row   = chunk >> 3;
        int c8    = chunk & 7;
        const float* px = &X[(size_t)(b * NS + s0 + row) * NEMB + h * 64 + c8 * 8];
        const float* pz = &Z[(size_t)(b * NS + s0 + row) * NEMB + h * 64 + c8 * 8];
        float4 a0 = *(const float4*)px, a1 = *(const float4*)(px + 4);
        float4 z0 = *(const float4*)pz, z1 = *(const float4*)(pz + 4);
        short8 xv, zv;
        ((uint*)&xv)[0] = cvt_pk(a0.x, a0.y);
        ((uint*)&xv)[1] = cvt_pk(a0.z, a0.w);
        ((uint*)&xv)[2] = cvt_pk(a1.x, a1.y);
        ((uint*)&xv)[3] = cvt_pk(a1.z, a1.w);
        ((uint*)&zv)[0] = cvt_pk(z0.x, z0.y);
        ((uint*)&zv)[1] = cvt_pk(z0.z, z0.w);
        ((uint*)&zv)[2] = cvt_pk(z1.x, z1.y);
        ((uint*)&zv)[3] = cvt_pk(z1.z, z1.w);
        *(short8*)((char*)xs + SWZ(row, c8 * 16)) = xv;
        *(short8*)((char*)zs + SWZ(row, c8 * 16)) = zv;
    }
    // stage pre-cast bf16 weights (no conversion)
#pragma unroll
    for (int c = 0; c < 2; ++c) {
        int chunk = c * 256 + t;
        int row   = chunk >> 3;
        int c8    = chunk & 7;
        short8 qv = *(const short8*)&Wqb[(size_t)h * 4096 + row * 64 + c8 * 8];
        short8 kv = *(const short8*)&Wkb[(size_t)h * 4096 + row * 64 + c8 * 8];
        short8 vv = *(const short8*)&Wvb[(size_t)h * 4096 + row * 64 + c8 * 8];
        *(short8*)((char*)wqs + SWZ(row, c8 * 16)) = qv;
        *(short8*)((char*)wks + SWZ(row, c8 * 16)) = kv;
        *(short8*)((char*)wvs + SWZ(row, c8 * 16)) = vv;
    }
    __syncthreads();

    floatx4 aq[2][4], ak[2][4], av[2][4];
#pragma unroll
    for (int i = 0; i < 2; ++i)
#pragma unroll
        for (int j = 0; j < 4; ++j) {
            aq[i][j] = (floatx4){0.f, 0.f, 0.f, 0.f};
            ak[i][j] = (floatx4){0.f, 0.f, 0.f, 0.f};
            av[i][j] = (floatx4){0.f, 0.f, 0.f, 0.f};
        }

#pragma unroll
    for (int kc = 0; kc < 2; ++kc) {
        short8 xa[2], za[2];
#pragma unroll
        for (int i = 0; i < 2; ++i) {
            int row = w * 32 + i * 16 + l16;
            xa[i] = *(const short8*)((const char*)xs + SWZ(row, kc * 64 + lg * 16));
            za[i] = *(const short8*)((const char*)zs + SWZ(row, kc * 64 + lg * 16));
        }
#pragma unroll
        for (int j = 0; j < 4; ++j) {
            int row = j * 16 + l16;
            short8 wqf = *(const short8*)((const char*)wqs + SWZ(row, kc * 64 + lg * 16));
            short8 wkf = *(const short8*)((const char*)wks + SWZ(row, kc * 64 + lg * 16));
            short8 wvf = *(const short8*)((const char*)wvs + SWZ(row, kc * 64 + lg * 16));
#pragma unroll
            for (int i = 0; i < 2; ++i) {
                aq[i][j] = __builtin_amdgcn_mfma_f32_16x16x32_bf16(xa[i], wqf, aq[i][j], 0, 0, 0);
                ak[i][j] = __builtin_amdgcn_mfma_f32_16x16x32_bf16(za[i], wkf, ak[i][j], 0, 0, 0);
                av[i][j] = __builtin_amdgcn_mfma_f32_16x16x32_bf16(za[i], wvf, av[i][j], 0, 0, 0);
            }
        }
    }

    float bqv[4], bkv[4], bvv[4];
#pragma unroll
    for (int j = 0; j < 4; ++j) {
        bqv[j] = bq[h * 64 + j * 16 + l16];
        bkv[j] = bk[h * 64 + j * 16 + l16];
        bvv[j] = bv[h * 64 + j * 16 + l16];
    }

#pragma unroll
    for (int i = 0; i < 2; ++i)
#pragma unroll
        for (int j = 0; j < 4; ++j) {
            int d = j * 16 + l16;
            int s = s0 + w * 32 + i * 16 + lg * 4;
            uint2 pv2;
            pv2.x = cvt_pk(av[i][j][0] + bvv[j], av[i][j][1] + bvv[j]);
            pv2.y = cvt_pk(av[i][j][2] + bvv[j], av[i][j][3] + bvv[j]);
            *(uint2*)&Vt[((size_t)bh * NHD + d) * NS + s] = pv2;
        }

    __syncthreads();
#pragma unroll
    for (int i = 0; i < 2; ++i)
#pragma unroll
        for (int j = 0; j < 4; ++j)
#pragma unroll
            for (int r = 0; r < 4; r += 2) {
                int sA = w * 32 + i * 16 + lg * 4 + r;
                uint uq = cvt_pk(aq[i][j][r] + bqv[j], aq[i][j][r + 1] + bqv[j]);
                uint uk = cvt_pk(ak[i][j][r] + bkv[j], ak[i][j][r + 1] + bkv[j]);
                xs[sA * 72 + j * 16 + l16]       = (ushort)uq;
                xs[(sA + 1) * 72 + j * 16 + l16] = (ushort)(uq >> 16);
                zs[sA * 72 + j * 16 + l16]       = (ushort)uk;
                zs[(sA + 1) * 72 + j * 16 + l16] = (ushort)(uk >> 16);
            }
    __syncthreads();
#pragma unroll
    for (int c = 0; c < 4; ++c) {
        int chunk = c * 256 + t;
        int row   = chunk >> 3;
        int c8    = chunk & 7;
        short8 qv = *(const short8*)&xs[row * 72 + c8 * 8];
        short8 kv = *(const short8*)&zs[row * 72 + c8 * 8];
        *(short8*)&Q[((size_t)bh * NS + s0 + row) * 64 + c8 * 8] = qv;
        *(short8*)&K[((size_t)bh * NS + s0 + row) * 64 + c8 * 8] = kv;
    }
}

// ---------------------------------------------------------------------------
// Kernel 2: MFMA flash attention (8 waves, 128 q rows, shared K/V tile, dbuf,
// 1 barrier/epoch, cvt_pk, complementary-tq placement). Staging now via
// global_load_lds: linear LDS dest (wave w bytes [w*1024,+1024)), source
// address pre-swizzled so the LDS image equals the SWZ layout (rule #21).
// ---------------------------------------------------------------------------
__global__ __launch_bounds__(512) void flash_attn(
    const ushort* __restrict__ Q, const ushort* __restrict__ K,
    const ushort* __restrict__ Vt, ushort* __restrict__ A)
{
    int bh = blockIdx.y;
    // complementary pairing: (x, bh) and (x, bh+16) sum to gridDim.x-1
    int tq = (bh < NH) ? ((gridDim.x - 1) - blockIdx.x) : blockIdx.x;
    int h = bh & (NH - 1), b = bh >> 4;

    __shared__ __align__(16) ushort k_lds[2][64 * 64];
    __shared__ __align__(16) ushort v_lds[2][64 * 64];
    __shared__ __align__(16) ushort p_lds[8][16 * 72];

    int t = threadIdx.x, w = t >> 6, l = t & 63;
    int l16 = l & 15, lg = l >> 4;
    int w4 = w & 3, wh = w >> 2;

    const ushort* Qb = Q + (size_t)bh * NS * NHD;
    const char* Kb8 = (const char*)(K + (size_t)bh * NS * NHD);
    const char* Vb8 = (const char*)(Vt + (size_t)bh * NHD * NS);

    int q0 = tq * 128;
    const float QSCALE = 0.125f * 1.44269504088896f;

    short8 qf[2];
#pragma unroll
    for (int c = 0; c < 2; ++c) {
        short8 raw = *(const short8*)&Qb[(size_t)(q0 + w * 16 + l16) * 64 + c * 32 + lg * 8];
#pragma unroll
        for (int j = 0; j < 4; ++j)
            ((uint*)&qf[c])[j] = cvt_pk(bf2f(((ushort*)&raw)[2 * j]) * QSCALE,
                                        bf2f(((ushort*)&raw)[2 * j + 1]) * QSCALE);
    }

    floatx4 ob[4];
#pragma unroll
    for (int d = 0; d < 4; ++d) ob[d] = (floatx4){0.f, 0.f, 0.f, 0.f};
    float m = -1e30f, ln = 0.f;

    // gload_lds staging: wave w owns rows w*8..w*8+7 (LDS bytes w*1024..+1024).
    // Source byte-col pre-swizzled so linear dest reproduces the SWZ image.
    int rowk = (w << 3) + (l >> 3);                        // 0..63
    int colb = ((l & 7) << 4) ^ (((l >> 3) & 7) << 4);     // inverse-swz source col
    const char* ksrc = Kb8 + (size_t)rowk * 128 + colb;    // + tile*8192
    const char* vsrc = Vb8 + (size_t)rowk * (NS * 2) + colb; // + tile*128

    // prologue: stage tile 0 (visible after the it=0 top barrier's vmcnt drain)
    gload16(ksrc, (char*)k_lds[0] + w * 1024);
    gload16(vsrc, (char*)v_lds[0] + w * 1024);

    int nt  = 2 * tq + 2;          // kv tiles 0 .. 2tq+1
    int lim = 2 * tq + wh;         // this wave's last (diagonal) tile

    for (int it = 0; it < nt; ++it) {
        __syncthreads();           // buf[cur] loads drained; reads of buf[nxt] done
        int cur = it & 1, nxt = cur ^ 1;
        if (it + 1 < nt) {         // async-stage next tile into the other buffer
            gload16(ksrc + (size_t)(it + 1) * 8192, (char*)k_lds[nxt] + w * 1024);
            gload16(vsrc + (size_t)(it + 1) * 128,  (char*)v_lds[nxt] + w * 1024);
        }

        if (it <= lim) {
            // ---- S^T: sv[stt][r] = S[k=stt*16+lg*4+r][q=l16] (log2 dom.)
            floatx4 sv[4];
#pragma unroll
            for (int stt = 0; stt < 4; ++stt) {
                floatx4 acc = {0.f, 0.f, 0.f, 0.f};
#pragma unroll
                for (int c = 0; c < 2; ++c) {
                    int row = stt * 16 + l16;
                    short8 kf = *(const short8*)((const char*)k_lds[cur] +
                                                 SWZ(row, c * 64 + lg * 16));
                    acc = __builtin_amdgcn_mfma_f32_16x16x32_bf16(kf, qf[c], acc, 0, 0, 0);
                }
                sv[stt] = acc;
            }
            if (it == lim) {       // diagonal tile for this wave
#pragma unroll
                for (int stt = 0; stt < 4; ++stt)
#pragma unroll
                    for (int r = 0; r < 4; ++r)
                        if (stt * 16 + lg * 4 + r > w4 * 16 + l16) sv[stt][r] = -1e30f;
            }

            // ---- softmax: in-register 16-max + 2 shuffles ----
            float p01 = fmaxf(fmaxf(sv[0][0], sv[0][1]), fmaxf(sv[0][2], sv[0][3]));
            float p23 = fmaxf(fmaxf(sv[1][0], sv[1][1]), fmaxf(sv[1][2], sv[1][3]));
            float p45 = fmaxf(fmaxf(sv[2][0], sv[2][1]), fmaxf(sv[2][2], sv[2][3]));
            float p67 = fmaxf(fmaxf(sv[3][0], sv[3][1]), fmaxf(sv[3][2], sv[3][3]));
            float pmax = fmaxf(fmaxf(p01, p23), fmaxf(p45, p67));
            pmax = fmaxf(pmax, __shfl_xor(pmax, 16, 64));
            pmax = fmaxf(pmax, __shfl_xor(pmax, 32, 64));

            if (!__all(pmax - m <= 8.0f)) {   // T13 defer-max (log2 units)
                float mn = fmaxf(m, pmax);
                float al = exp2f(m - mn);
                m = mn;
                ln *= al;
#pragma unroll
                for (int d = 0; d < 4; ++d)
#pragma unroll
                    for (int r = 0; r < 4; ++r) ob[d][r] *= al;
            }

            float rs = 0.f;
#pragma unroll
            for (int stt = 0; stt < 4; ++stt)
#pragma unroll
                for (int r = 0; r < 4; ++r) {
                    float p = exp2f(sv[stt][r] - m);
                    sv[stt][r] = p;
                    rs += p;
                }
            rs += __shfl_xor(rs, 16, 64);
            rs += __shfl_xor(rs, 32, 64);
            ln += rs;

            // ---- P -> p_lds[q][k] via packed cvt, then PV: O^T = V^T P ----
#pragma unroll
            for (int stt = 0; stt < 4; ++stt) {
                uint2 pk2;
                pk2.x = cvt_pk(sv[stt][0], sv[stt][1]);
                pk2.y = cvt_pk(sv[stt][2], sv[stt][3]);
                *(uint2*)&p_lds[w][l16 * 72 + stt * 16 + lg * 4] = pk2;
            }

#pragma unroll
            for (int ks = 0; ks < 2; ++ks) {
                short8 pf = *(const short8*)((const char*)&p_lds[w][0] +
                                             (l16 * 144 + ks * 64 + lg * 16));
#pragma unroll
                for (int d = 0; d < 4; ++d) {
                    int vrow = d * 16 + l16;
                    short8 vf = *(const short8*)((const char*)v_lds[cur] +
                                                 SWZ(vrow, ks * 64 + lg * 16));
                    ob[d] = __builtin_amdgcn_mfma_f32_16x16x32_bf16(vf, pf, ob[d], 0, 0, 0);
                }
            }
        }
    }

    // epilogue: lane owns q = q0 + w*16 + l16; d = d0*16 + lg*4 + r
    float inv = 1.0f / ln;
    int qq = q0 + w * 16 + l16;
#pragma unroll
    for (int d = 0; d < 4; ++d) {
        uint2 ov;
        ov.x = cvt_pk(ob[d][0] * inv, ob[d][1] * inv);
        ov.y = cvt_pk(ob[d][2] * inv, ob[d][3] * inv);
        *(uint2*)&A[(size_t)(b * NS + qq) * NEMB + h * 64 + d * 16 + lg * 4] = ov;
    }
}

// ---------------------------------------------------------------------------
// Kernel 3: Y = A @ Wo^T + bo via bf16 MFMA, fp32 accum.
// 64x128 tile, grid (64,8) = 512 blocks = 2/CU.
// ---------------------------------------------------------------------------
__global__ __launch_bounds__(256) void out_gemm_mfma(
    const ushort* __restrict__ Aq, const ushort* __restrict__ Wob,
    const float* __restrict__ bo, float* __restrict__ Y)
{
    int m0 = blockIdx.x * 64;
    int n0 = blockIdx.y * 128;

    __shared__ __align__(16) ushort As[64 * 64];    // [m][k], swizzled
    __shared__ __align__(16) ushort Bs[128 * 64];   // [n][k], swizzled

    int t = threadIdx.x, w = t >> 6, l = t & 63;
    int l16 = l & 15, lg = l >> 4;
    int wr = w >> 1, wc = w & 1;    // wave tile: rows wr*32, cols wc*64

    floatx4 acc[2][4];
#pragma unroll
    for (int i = 0; i < 2; ++i)
#pragma unroll
        for (int j = 0; j < 4; ++j) acc[i][j] = (floatx4){0.f, 0.f, 0.f, 0.f};

    for (int kt = 0; kt < 16; ++kt) {
        __syncthreads();
#pragma unroll
        for (int i = 0; i < 2; ++i) {               // A: 512 chunks
            int chunk = i * 256 + t;
            int row   = chunk >> 3;
            int c16   = chunk & 7;
            short8 av = *(const short8*)&Aq[(size_t)(m0 + row) * 1024 + kt * 64 + c16 * 8];
            *(short8*)((char*)As + SWZ(row, c16 * 16)) = av;
        }
#pragma unroll
        for (int i = 0; i < 4; ++i) {               // B: 1024 chunks
            int chunk = i * 256 + t;
            int row   = chunk >> 3;
            int c16   = chunk & 7;
            short8 bv = *(const short8*)&Wob[(size_t)(n0 + row) * 1024 + kt * 64 + c16 * 8];
            *(short8*)((char*)Bs + SWZ(row, c16 * 16)) = bv;
        }
        __syncthreads();
#pragma unroll
        for (int kc = 0; kc < 2; ++kc) {
            short8 af[2], bf[4];
#pragma unroll
            for (int i = 0; i < 2; ++i) {
                int arow = wr * 32 + i * 16 + l16;
                af[i] = *(const short8*)((const char*)As + SWZ(arow, kc * 64 + lg * 16));
            }
#pragma unroll
            for (int j = 0; j < 4; ++j) {
                int brow = wc * 64 + j * 16 + l16;
                bf[j] = *(const short8*)((const char*)Bs + SWZ(brow, kc * 64 + lg * 16));
            }
#pragma unroll
            for (int i = 0; i < 2; ++i)
#pragma unroll
                for (int j = 0; j < 4; ++j)
                    acc[i][j] = __builtin_amdgcn_mfma_f32_16x16x32_bf16(
                        af[i], bf[j], acc[i][j], 0, 0, 0);
        }
    }
#pragma unroll
    for (int i = 0; i < 2; ++i)
#pragma unroll
        for (int j = 0; j < 4; ++j) {
            int nn = n0 + wc * 64 + j * 16 + l16;
            float bb = bo[nn];
#pragma unroll
            for (int r = 0; r < 4; ++r) {
                int mm = m0 + wr * 32 + i * 16 + lg * 4 + r;
                Y[(size_t)mm * 1024 + nn] = acc[i][j][r] + bb;
            }
        }
}

// ---------------------------------------------------------------------------
extern "C" void kernel_launch(void* const* d_in, const int* in_sizes, int n_in,
                              void* d_out, int out_size, void* d_ws, size_t ws_size,
                              hipStream_t stream) {
    const float* X  = (const float*)d_in[0];
    const float* Z  = (const float*)d_in[1];
    const float* Wq = (const float*)d_in[2];
    const float* bq = (const float*)d_in[3];
    const float* Wk = (const float*)d_in[4];
    const float* bk = (const float*)d_in[5];
    const float* Wv = (const float*)d_in[6];
    const float* bv = (const float*)d_in[7];
    const float* Wo = (const float*)d_in[8];
    const float* bo = (const float*)d_in[9];
    float* out = (float*)d_out;

    const size_t NQ = (size_t)NB * NH * NS * NHD;   // 4M elems
    ushort* Qd  = (ushort*)d_ws;
    ushort* Kd  = Qd + NQ;
    ushort* Vtd = Kd + NQ;
    ushort* Ad  = Vtd + NQ;
    ushort* Wqb = Ad + NQ;                          // 65536 elems
    ushort* Wkb = Wqb + 65536;
    ushort* Wvb = Wkb + 65536;
    ushort* Wob = Wvb + 65536;                      // 1M elems

    w_cast<<<dim3(608), 256, 0, stream>>>(Wq, Wk, Wv, Wo, Wqb, Wkb, Wvb, Wob);
    qkv_mfma<<<dim3(NS / 128, NB * NH), 256, 0, stream>>>(
        X, Z, Wqb, bq, Wkb, bk, Wvb, bv, Qd, Kd, Vtd);
    flash_attn<<<dim3(NS / 128, NB * NH), 512, 0, stream>>>(Qd, Kd, Vtd, Ad);
    out_gemm_mfma<<<dim3(64, 8), 256, 0, stream>>>(Ad, Wob, bo, out);
}

// Round 17
// 88.686 us; speedup vs baseline: 1.0908x; 1.0908x over previous
//
#include <hip/hip_runtime.h>
#include <hip/hip_bf16.h>
#include <math.h>

#define NB   2
#define NS   2048
#define NEMB 1024
#define NH   16
#define NHD  64

typedef __attribute__((ext_vector_type(8))) short short8;
typedef __attribute__((ext_vector_type(4))) float floatx4;

static __device__ __forceinline__ float bf2f(ushort u) {
    union { uint u; float f; } x; x.u = ((uint)u) << 16;
    return x.f;
}
// HW packed convert: dword = [bf16(lo) | bf16(hi)<<16]
static __device__ __forceinline__ uint cvt_pk(float lo, float hi) {
    uint r;
    asm("v_cvt_pk_bf16_f32 %0, %1, %2" : "=v"(r) : "v"(lo), "v"(hi));
    return r;
}

#define SWZ(row, bytecol) (((row) * 128 + (bytecol)) ^ (((row) & 7) << 4))

// ---------------------------------------------------------------------------
// Kernel 0: cast ALL weights fp32 -> bf16 (Wq,Wk,Wv: 64K elems each; Wo: 1M).
// ---------------------------------------------------------------------------
__global__ __launch_bounds__(256) void w_cast(
    const float* __restrict__ Wq, const float* __restrict__ Wk,
    const float* __restrict__ Wv, const float* __restrict__ Wo,
    ushort* __restrict__ Wqb, ushort* __restrict__ Wkb,
    ushort* __restrict__ Wvb, ushort* __restrict__ Wob)
{
    int i = (blockIdx.x * 256 + threadIdx.x) * 8;
    const float* src;
    ushort* dst;
    int off;
    if (i < 196608) {                    // 3 x 65536 (= NH*NHD*NHD)
        int sel = i >> 16;
        off = i & 65535;
        src = sel == 0 ? Wq : (sel == 1 ? Wk : Wv);
        dst = sel == 0 ? Wqb : (sel == 1 ? Wkb : Wvb);
    } else {
        off = i - 196608;
        src = Wo;
        dst = Wob;
    }
    float4 a = *(const float4*)&src[off];
    float4 b = *(const float4*)&src[off + 4];
    short8 o;
    ((uint*)&o)[0] = cvt_pk(a.x, a.y);
    ((uint*)&o)[1] = cvt_pk(a.z, a.w);
    ((uint*)&o)[2] = cvt_pk(b.x, b.y);
    ((uint*)&o)[3] = cvt_pk(b.z, b.w);
    *(short8*)&dst[off] = o;
}

// ---------------------------------------------------------------------------
// Kernel 1: fused QKV projection via MFMA (fp32 X/Z, bf16 weights, bf16 out),
// emits Q, K and TRANSPOSED V (Vt[b,h,d,s]). grid = (S/128, B*H), block 256.
// ---------------------------------------------------------------------------
__global__ __launch_bounds__(256) void qkv_mfma(
    const float* __restrict__ X, const float* __restrict__ Z,
    const ushort* __restrict__ Wqb, const float* __restrict__ bq,
    const ushort* __restrict__ Wkb, const float* __restrict__ bk,
    const ushort* __restrict__ Wvb, const float* __restrict__ bv,
    ushort* __restrict__ Q, ushort* __restrict__ K, ushort* __restrict__ Vt)
{
    int st = blockIdx.x, bh = blockIdx.y;
    int h = bh & (NH - 1), b = bh >> 4;
    int s0 = st * 128;

    __shared__ __align__(16) ushort xs[128 * 72];
    __shared__ __align__(16) ushort zs[128 * 72];
    __shared__ __align__(16) ushort wqs[64 * 64], wks[64 * 64], wvs[64 * 64];

    int t = threadIdx.x, w = t >> 6, l = t & 63;
    int l16 = l & 15, lg = l >> 4;

#pragma unroll
    for (int c = 0; c < 4; ++c) {
        int chunk = c * 256 + t;
        int row   = chunk >> 3;
        int c8    = chunk & 7;
        const float* px = &X[(size_t)(b * NS + s0 + row) * NEMB + h * 64 + c8 * 8];
        const float* pz = &Z[(size_t)(b * NS + s0 + row) * NEMB + h * 64 + c8 * 8];
        float4 a0 = *(const float4*)px, a1 = *(const float4*)(px + 4);
        float4 z0 = *(const float4*)pz, z1 = *(const float4*)(pz + 4);
        short8 xv, zv;
        ((uint*)&xv)[0] = cvt_pk(a0.x, a0.y);
        ((uint*)&xv)[1] = cvt_pk(a0.z, a0.w);
        ((uint*)&xv)[2] = cvt_pk(a1.x, a1.y);
        ((uint*)&xv)[3] = cvt_pk(a1.z, a1.w);
        ((uint*)&zv)[0] = cvt_pk(z0.x, z0.y);
        ((uint*)&zv)[1] = cvt_pk(z0.z, z0.w);
        ((uint*)&zv)[2] = cvt_pk(z1.x, z1.y);
        ((uint*)&zv)[3] = cvt_pk(z1.z, z1.w);
        *(short8*)((char*)xs + SWZ(row, c8 * 16)) = xv;
        *(short8*)((char*)zs + SWZ(row, c8 * 16)) = zv;
    }
    // stage pre-cast bf16 weights (no conversion)
#pragma unroll
    for (int c = 0; c < 2; ++c) {
        int chunk = c * 256 + t;
        int row   = chunk >> 3;
        int c8    = chunk & 7;
        short8 qv = *(const short8*)&Wqb[(size_t)h * 4096 + row * 64 + c8 * 8];
        short8 kv = *(const short8*)&Wkb[(size_t)h * 4096 + row * 64 + c8 * 8];
        short8 vv = *(const short8*)&Wvb[(size_t)h * 4096 + row * 64 + c8 * 8];
        *(short8*)((char*)wqs + SWZ(row, c8 * 16)) = qv;
        *(short8*)((char*)wks + SWZ(row, c8 * 16)) = kv;
        *(short8*)((char*)wvs + SWZ(row, c8 * 16)) = vv;
    }
    __syncthreads();

    floatx4 aq[2][4], ak[2][4], av[2][4];
#pragma unroll
    for (int i = 0; i < 2; ++i)
#pragma unroll
        for (int j = 0; j < 4; ++j) {
            aq[i][j] = (floatx4){0.f, 0.f, 0.f, 0.f};
            ak[i][j] = (floatx4){0.f, 0.f, 0.f, 0.f};
            av[i][j] = (floatx4){0.f, 0.f, 0.f, 0.f};
        }

#pragma unroll
    for (int kc = 0; kc < 2; ++kc) {
        short8 xa[2], za[2];
#pragma unroll
        for (int i = 0; i < 2; ++i) {
            int row = w * 32 + i * 16 + l16;
            xa[i] = *(const short8*)((const char*)xs + SWZ(row, kc * 64 + lg * 16));
            za[i] = *(const short8*)((const char*)zs + SWZ(row, kc * 64 + lg * 16));
        }
#pragma unroll
        for (int j = 0; j < 4; ++j) {
            int row = j * 16 + l16;
            short8 wqf = *(const short8*)((const char*)wqs + SWZ(row, kc * 64 + lg * 16));
            short8 wkf = *(const short8*)((const char*)wks + SWZ(row, kc * 64 + lg * 16));
            short8 wvf = *(const short8*)((const char*)wvs + SWZ(row, kc * 64 + lg * 16));
#pragma unroll
            for (int i = 0; i < 2; ++i) {
                aq[i][j] = __builtin_amdgcn_mfma_f32_16x16x32_bf16(xa[i], wqf, aq[i][j], 0, 0, 0);
                ak[i][j] = __builtin_amdgcn_mfma_f32_16x16x32_bf16(za[i], wkf, ak[i][j], 0, 0, 0);
                av[i][j] = __builtin_amdgcn_mfma_f32_16x16x32_bf16(za[i], wvf, av[i][j], 0, 0, 0);
            }
        }
    }

    float bqv[4], bkv[4], bvv[4];
#pragma unroll
    for (int j = 0; j < 4; ++j) {
        bqv[j] = bq[h * 64 + j * 16 + l16];
        bkv[j] = bk[h * 64 + j * 16 + l16];
        bvv[j] = bv[h * 64 + j * 16 + l16];
    }

#pragma unroll
    for (int i = 0; i < 2; ++i)
#pragma unroll
        for (int j = 0; j < 4; ++j) {
            int d = j * 16 + l16;
            int s = s0 + w * 32 + i * 16 + lg * 4;
            uint2 pv2;
            pv2.x = cvt_pk(av[i][j][0] + bvv[j], av[i][j][1] + bvv[j]);
            pv2.y = cvt_pk(av[i][j][2] + bvv[j], av[i][j][3] + bvv[j]);
            *(uint2*)&Vt[((size_t)bh * NHD + d) * NS + s] = pv2;
        }

    __syncthreads();
#pragma unroll
    for (int i = 0; i < 2; ++i)
#pragma unroll
        for (int j = 0; j < 4; ++j)
#pragma unroll
            for (int r = 0; r < 4; r += 2) {
                int sA = w * 32 + i * 16 + lg * 4 + r;
                uint uq = cvt_pk(aq[i][j][r] + bqv[j], aq[i][j][r + 1] + bqv[j]);
                uint uk = cvt_pk(ak[i][j][r] + bkv[j], ak[i][j][r + 1] + bkv[j]);
                xs[sA * 72 + j * 16 + l16]       = (ushort)uq;
                xs[(sA + 1) * 72 + j * 16 + l16] = (ushort)(uq >> 16);
                zs[sA * 72 + j * 16 + l16]       = (ushort)uk;
                zs[(sA + 1) * 72 + j * 16 + l16] = (ushort)(uk >> 16);
            }
    __syncthreads();
#pragma unroll
    for (int c = 0; c < 4; ++c) {
        int chunk = c * 256 + t;
        int row   = chunk >> 3;
        int c8    = chunk & 7;
        short8 qv = *(const short8*)&xs[row * 72 + c8 * 8];
        short8 kv = *(const short8*)&zs[row * 72 + c8 * 8];
        *(short8*)&Q[((size_t)bh * NS + s0 + row) * 64 + c8 * 8] = qv;
        *(short8*)&K[((size_t)bh * NS + s0 + row) * 64 + c8 * 8] = kv;
    }
}

// ---------------------------------------------------------------------------
// Kernel 2: MFMA flash attention (8 waves, 128 q rows, shared K/V tile, dbuf,
// 1 barrier/epoch, cvt_pk, complementary-tq placement, REG-staging restored
// [R16: gload_lds's collective vmcnt(0)-at-barrier drain regressed 23%]).
// New: deferred-ln — per-lane partial row-sums, single cross-lane reduce in
// the epilogue (removes 2 ds_bpermute from every epoch's serial chain).
// ---------------------------------------------------------------------------
__global__ __launch_bounds__(512) void flash_attn(
    const ushort* __restrict__ Q, const ushort* __restrict__ K,
    const ushort* __restrict__ Vt, ushort* __restrict__ A)
{
    int bh = blockIdx.y;
    // complementary pairing: (x, bh) and (x, bh+16) sum to gridDim.x-1
    int tq = (bh < NH) ? ((gridDim.x - 1) - blockIdx.x) : blockIdx.x;
    int h = bh & (NH - 1), b = bh >> 4;

    __shared__ __align__(16) ushort k_lds[2][64 * 64];
    __shared__ __align__(16) ushort v_lds[2][64 * 64];
    __shared__ __align__(16) ushort p_lds[8][16 * 72];

    int t = threadIdx.x, w = t >> 6, l = t & 63;
    int l16 = l & 15, lg = l >> 4;
    int w4 = w & 3, wh = w >> 2;

    const ushort* Qb = Q + (size_t)bh * NS * NHD;
    const ushort* Kb = K + (size_t)bh * NS * NHD;
    const ushort* Vb = Vt + (size_t)bh * NHD * NS;

    int q0 = tq * 128;
    const float QSCALE = 0.125f * 1.44269504088896f;

    short8 qf[2];
#pragma unroll
    for (int c = 0; c < 2; ++c) {
        short8 raw = *(const short8*)&Qb[(size_t)(q0 + w * 16 + l16) * 64 + c * 32 + lg * 8];
#pragma unroll
        for (int j = 0; j < 4; ++j)
            ((uint*)&qf[c])[j] = cvt_pk(bf2f(((ushort*)&raw)[2 * j]) * QSCALE,
                                        bf2f(((ushort*)&raw)[2 * j + 1]) * QSCALE);
    }

    floatx4 ob[4];
#pragma unroll
    for (int d = 0; d < 4; ++d) ob[d] = (floatx4){0.f, 0.f, 0.f, 0.f};
    float m = -1e30f, ln = 0.f;   // ln: per-lane PARTIAL sum (reduced at end)

    // block-wide staging: 512 threads x 16B = one 64x64 bf16 tile each for K,V
    int rrow = t >> 3, rcb = (t & 7) * 8;

    short8 kpre, vpre;
    kpre = *(const short8*)&Kb[(size_t)rrow * 64 + rcb];
    vpre = *(const short8*)&Vb[(size_t)rrow * NS + rcb];
    *(short8*)((char*)k_lds[0] + SWZ(rrow, rcb * 2)) = kpre;
    *(short8*)((char*)v_lds[0] + SWZ(rrow, rcb * 2)) = vpre;

    int nt  = 2 * tq + 2;          // kv tiles 0 .. 2tq+1
    int lim = 2 * tq + wh;         // this wave's last (diagonal) tile

    for (int it = 0; it < nt; ++it) {
        __syncthreads();           // buf[it&1] ready; prior reads of buf[nxt] done
        int cur = it & 1, nxt = cur ^ 1;
        bool have_next = (it + 1 < nt);
        if (have_next) {           // issue loads early (hide under compute)
            kpre = *(const short8*)&Kb[(size_t)((it + 1) * 64 + rrow) * 64 + rcb];
            vpre = *(const short8*)&Vb[(size_t)rrow * NS + (it + 1) * 64 + rcb];
        }

        if (it <= lim) {
            // ---- S^T: sv[stt][r] = S[k=stt*16+lg*4+r][q=l16] (log2 dom.)
            floatx4 sv[4];
#pragma unroll
            for (int stt = 0; stt < 4; ++stt) {
                floatx4 acc = {0.f, 0.f, 0.f, 0.f};
#pragma unroll
                for (int c = 0; c < 2; ++c) {
                    int row = stt * 16 + l16;
                    short8 kf = *(const short8*)((const char*)k_lds[cur] +
                                                 SWZ(row, c * 64 + lg * 16));
                    acc = __builtin_amdgcn_mfma_f32_16x16x32_bf16(kf, qf[c], acc, 0, 0, 0);
                }
                sv[stt] = acc;
            }
            if (it == lim) {       // diagonal tile for this wave
#pragma unroll
                for (int stt = 0; stt < 4; ++stt)
#pragma unroll
                    for (int r = 0; r < 4; ++r)
                        if (stt * 16 + lg * 4 + r > w4 * 16 + l16) sv[stt][r] = -1e30f;
            }

            // ---- softmax: in-register 16-max + 2 shuffles (max only) ----
            float p01 = fmaxf(fmaxf(sv[0][0], sv[0][1]), fmaxf(sv[0][2], sv[0][3]));
            float p23 = fmaxf(fmaxf(sv[1][0], sv[1][1]), fmaxf(sv[1][2], sv[1][3]));
            float p45 = fmaxf(fmaxf(sv[2][0], sv[2][1]), fmaxf(sv[2][2], sv[2][3]));
            float p67 = fmaxf(fmaxf(sv[3][0], sv[3][1]), fmaxf(sv[3][2], sv[3][3]));
            float pmax = fmaxf(fmaxf(p01, p23), fmaxf(p45, p67));
            pmax = fmaxf(pmax, __shfl_xor(pmax, 16, 64));
            pmax = fmaxf(pmax, __shfl_xor(pmax, 32, 64));

            if (!__all(pmax - m <= 8.0f)) {   // T13 defer-max (log2 units)
                float mn = fmaxf(m, pmax);
                float al = exp2f(m - mn);
                m = mn;
                ln *= al;                      // scales the partial sum too
#pragma unroll
                for (int d = 0; d < 4; ++d)
#pragma unroll
                    for (int r = 0; r < 4; ++r) ob[d][r] *= al;
            }

            float rs = 0.f;
#pragma unroll
            for (int stt = 0; stt < 4; ++stt)
#pragma unroll
                for (int r = 0; r < 4; ++r) {
                    float p = exp2f(sv[stt][r] - m);
                    sv[stt][r] = p;
                    rs += p;
                }
            ln += rs;                          // partial only; reduce at end

            // ---- P -> p_lds[q][k] via packed cvt, then PV: O^T = V^T P ----
#pragma unroll
            for (int stt = 0; stt < 4; ++stt) {
                uint2 pk2;
                pk2.x = cvt_pk(sv[stt][0], sv[stt][1]);
                pk2.y = cvt_pk(sv[stt][2], sv[stt][3]);
                *(uint2*)&p_lds[w][l16 * 72 + stt * 16 + lg * 4] = pk2;
            }

#pragma unroll
            for (int ks = 0; ks < 2; ++ks) {
                short8 pf = *(const short8*)((const char*)&p_lds[w][0] +
                                             (l16 * 144 + ks * 64 + lg * 16));
#pragma unroll
                for (int d = 0; d < 4; ++d) {
                    int vrow = d * 16 + l16;
                    short8 vf = *(const short8*)((const char*)v_lds[cur] +
                                                 SWZ(vrow, ks * 64 + lg * 16));
                    ob[d] = __builtin_amdgcn_mfma_f32_16x16x32_bf16(vf, pf, ob[d], 0, 0, 0);
                }
            }
        }

        if (have_next) {           // write prefetched tile into the other buffer
            *(short8*)((char*)k_lds[nxt] + SWZ(rrow, rcb * 2)) = kpre;
            *(short8*)((char*)v_lds[nxt] + SWZ(rrow, rcb * 2)) = vpre;
        }
    }

    // epilogue: single ln reduce (valid: all 4 lanes of a q-column shared m
    // at every step, so partials scale/add exactly as the eager reduce did)
    float lt = ln;
    lt += __shfl_xor(lt, 16, 64);
    lt += __shfl_xor(lt, 32, 64);
    float inv = 1.0f / lt;
    int qq = q0 + w * 16 + l16;
#pragma unroll
    for (int d = 0; d < 4; ++d) {
        uint2 ov;
        ov.x = cvt_pk(ob[d][0] * inv, ob[d][1] * inv);
        ov.y = cvt_pk(ob[d][2] * inv, ob[d][3] * inv);
        *(uint2*)&A[(size_t)(b * NS + qq) * NEMB + h * 64 + d * 16 + lg * 4] = ov;
    }
}

// ---------------------------------------------------------------------------
// Kernel 3: Y = A @ Wo^T + bo via bf16 MFMA, fp32 accum.
// 64x128 tile, grid (64,8) = 512 blocks = 2/CU.
// ---------------------------------------------------------------------------
__global__ __launch_bounds__(256) void out_gemm_mfma(
    const ushort* __restrict__ Aq, const ushort* __restrict__ Wob,
    const float* __restrict__ bo, float* __restrict__ Y)
{
    int m0 = blockIdx.x * 64;
    int n0 = blockIdx.y * 128;

    __shared__ __align__(16) ushort As[64 * 64];    // [m][k], swizzled
    __shared__ __align__(16) ushort Bs[128 * 64];   // [n][k], swizzled

    int t = threadIdx.x, w = t >> 6, l = t & 63;
    int l16 = l & 15, lg = l >> 4;
    int wr = w >> 1, wc = w & 1;    // wave tile: rows wr*32, cols wc*64

    floatx4 acc[2][4];
#pragma unroll
    for (int i = 0; i < 2; ++i)
#pragma unroll
        for (int j = 0; j < 4; ++j) acc[i][j] = (floatx4){0.f, 0.f, 0.f, 0.f};

    for (int kt = 0; kt < 16; ++kt) {
        __syncthreads();
#pragma unroll
        for (int i = 0; i < 2; ++i) {               // A: 512 chunks
            int chunk = i * 256 + t;
            int row   = chunk >> 3;
            int c16   = chunk & 7;
            short8 av = *(const short8*)&Aq[(size_t)(m0 + row) * 1024 + kt * 64 + c16 * 8];
            *(short8*)((char*)As + SWZ(row, c16 * 16)) = av;
        }
#pragma unroll
        for (int i = 0; i < 4; ++i) {               // B: 1024 chunks
            int chunk = i * 256 + t;
            int row   = chunk >> 3;
            int c16   = chunk & 7;
            short8 bv = *(const short8*)&Wob[(size_t)(n0 + row) * 1024 + kt * 64 + c16 * 8];
            *(short8*)((char*)Bs + SWZ(row, c16 * 16)) = bv;
        }
        __syncthreads();
#pragma unroll
        for (int kc = 0; kc < 2; ++kc) {
            short8 af[2], bf[4];
#pragma unroll
            for (int i = 0; i < 2; ++i) {
                int arow = wr * 32 + i * 16 + l16;
                af[i] = *(const short8*)((const char*)As + SWZ(arow, kc * 64 + lg * 16));
            }
#pragma unroll
            for (int j = 0; j < 4; ++j) {
                int brow = wc * 64 + j * 16 + l16;
                bf[j] = *(const short8*)((const char*)Bs + SWZ(brow, kc * 64 + lg * 16));
            }
#pragma unroll
            for (int i = 0; i < 2; ++i)
#pragma unroll
                for (int j = 0; j < 4; ++j)
                    acc[i][j] = __builtin_amdgcn_mfma_f32_16x16x32_bf16(
                        af[i], bf[j], acc[i][j], 0, 0, 0);
        }
    }
#pragma unroll
    for (int i = 0; i < 2; ++i)
#pragma unroll
        for (int j = 0; j < 4; ++j) {
            int nn = n0 + wc * 64 + j * 16 + l16;
            float bb = bo[nn];
#pragma unroll
            for (int r = 0; r < 4; ++r) {
                int mm = m0 + wr * 32 + i * 16 + lg * 4 + r;
                Y[(size_t)mm * 1024 + nn] = acc[i][j][r] + bb;
            }
        }
}

// ---------------------------------------------------------------------------
extern "C" void kernel_launch(void* const* d_in, const int* in_sizes, int n_in,
                              void* d_out, int out_size, void* d_ws, size_t ws_size,
                              hipStream_t stream) {
    const float* X  = (const float*)d_in[0];
    const float* Z  = (const float*)d_in[1];
    const float* Wq = (const float*)d_in[2];
    const float* bq = (const float*)d_in[3];
    const float* Wk = (const float*)d_in[4];
    const float* bk = (const float*)d_in[5];
    const float* Wv = (const float*)d_in[6];
    const float* bv = (const float*)d_in[7];
    const float* Wo = (const float*)d_in[8];
    const float* bo = (const float*)d_in[9];
    float* out = (float*)d_out;

    const size_t NQ = (size_t)NB * NH * NS * NHD;   // 4M elems
    ushort* Qd  = (ushort*)d_ws;
    ushort* Kd  = Qd + NQ;
    ushort* Vtd = Kd + NQ;
    ushort* Ad  = Vtd + NQ;
    ushort* Wqb = Ad + NQ;                          // 65536 elems
    ushort* Wkb = Wqb + 65536;
    ushort* Wvb = Wkb + 65536;
    ushort* Wob = Wvb + 65536;                      // 1M elems

    w_cast<<<dim3(608), 256, 0, stream>>>(Wq, Wk, Wv, Wo, Wqb, Wkb, Wvb, Wob);
    qkv_mfma<<<dim3(NS / 128, NB * NH), 256, 0, stream>>>(
        X, Z, Wqb, bq, Wkb, bk, Wvb, bv, Qd, Kd, Vtd);
    flash_attn<<<dim3(NS / 128, NB * NH), 512, 0, stream>>>(Qd, Kd, Vtd, Ad);
    out_gemm_mfma<<<dim3(64, 8), 256, 0, stream>>>(Ad, Wob, bo, out);
}

// Round 18
// 83.164 us; speedup vs baseline: 1.1632x; 1.0664x over previous
//
#include <hip/hip_runtime.h>
#include <hip/hip_bf16.h>
#include <math.h>

#define NB   2
#define NS   2048
#define NEMB 1024
#define NH   16
#define NHD  64

typedef __attribute__((ext_vector_type(8))) short short8;
typedef __attribute__((ext_vector_type(4))) float floatx4;

static __device__ __forceinline__ float bf2f(ushort u) {
    union { uint u; float f; } x; x.u = ((uint)u) << 16;
    return x.f;
}
// HW packed convert: dword = [bf16(lo) | bf16(hi)<<16]
static __device__ __forceinline__ uint cvt_pk(float lo, float hi) {
    uint r;
    asm("v_cvt_pk_bf16_f32 %0, %1, %2" : "=v"(r) : "v"(lo), "v"(hi));
    return r;
}
// async global->LDS, 16B/lane; LDS dest = wave-uniform base + lane*16
static __device__ __forceinline__ void gload16(const void* g, void* s) {
    __builtin_amdgcn_global_load_lds(
        (const __attribute__((address_space(1))) void*)g,
        (__attribute__((address_space(3))) void*)s, 16, 0, 0);
}

#define SWZ(row, bytecol) (((row) * 128 + (bytecol)) ^ (((row) & 7) << 4))

// ---------------------------------------------------------------------------
// Kernel 0: cast ALL weights fp32 -> bf16 (Wq,Wk,Wv: 64K elems each; Wo: 1M).
// ---------------------------------------------------------------------------
__global__ __launch_bounds__(256) void w_cast(
    const float* __restrict__ Wq, const float* __restrict__ Wk,
    const float* __restrict__ Wv, const float* __restrict__ Wo,
    ushort* __restrict__ Wqb, ushort* __restrict__ Wkb,
    ushort* __restrict__ Wvb, ushort* __restrict__ Wob)
{
    int i = (blockIdx.x * 256 + threadIdx.x) * 8;
    const float* src;
    ushort* dst;
    int off;
    if (i < 196608) {                    // 3 x 65536 (= NH*NHD*NHD)
        int sel = i >> 16;
        off = i & 65535;
        src = sel == 0 ? Wq : (sel == 1 ? Wk : Wv);
        dst = sel == 0 ? Wqb : (sel == 1 ? Wkb : Wvb);
    } else {
        off = i - 196608;
        src = Wo;
        dst = Wob;
    }
    float4 a = *(const float4*)&src[off];
    float4 b = *(const float4*)&src[off + 4];
    short8 o;
    ((uint*)&o)[0] = cvt_pk(a.x, a.y);
    ((uint*)&o)[1] = cvt_pk(a.z, a.w);
    ((uint*)&o)[2] = cvt_pk(b.x, b.y);
    ((uint*)&o)[3] = cvt_pk(b.z, b.w);
    *(short8*)&dst[off] = o;
}

// ---------------------------------------------------------------------------
// Kernel 1: fused QKV projection via MFMA (fp32 X/Z, bf16 weights, bf16 out),
// emits Q, K and TRANSPOSED V (Vt[b,h,d,s]). grid = (S/128, B*H), block 256.
// ---------------------------------------------------------------------------
__global__ __launch_bounds__(256) void qkv_mfma(
    const float* __restrict__ X, const float* __restrict__ Z,
    const ushort* __restrict__ Wqb, const float* __restrict__ bq,
    const ushort* __restrict__ Wkb, const float* __restrict__ bk,
    const ushort* __restrict__ Wvb, const float* __restrict__ bv,
    ushort* __restrict__ Q, ushort* __restrict__ K, ushort* __restrict__ Vt)
{
    int st = blockIdx.x, bh = blockIdx.y;
    int h = bh & (NH - 1), b = bh >> 4;
    int s0 = st * 128;

    __shared__ __align__(16) ushort xs[128 * 72];
    __shared__ __align__(16) ushort zs[128 * 72];
    __shared__ __align__(16) ushort wqs[64 * 64], wks[64 * 64], wvs[64 * 64];

    int t = threadIdx.x, w = t >> 6, l = t & 63;
    int l16 = l & 15, lg = l >> 4;

#pragma unroll
    for (int c = 0; c < 4; ++c) {
        int chunk = c * 256 + t;
        int row   = chunk >> 3;
        int c8    = chunk & 7;
        const float* px = &X[(size_t)(b * NS + s0 + row) * NEMB + h * 64 + c8 * 8];
        const float* pz = &Z[(size_t)(b * NS + s0 + row) * NEMB + h * 64 + c8 * 8];
        float4 a0 = *(const float4*)px, a1 = *(const float4*)(px + 4);
        float4 z0 = *(const float4*)pz, z1 = *(const float4*)(pz + 4);
        short8 xv, zv;
        ((uint*)&xv)[0] = cvt_pk(a0.x, a0.y);
        ((uint*)&xv)[1] = cvt_pk(a0.z, a0.w);
        ((uint*)&xv)[2] = cvt_pk(a1.x, a1.y);
        ((uint*)&xv)[3] = cvt_pk(a1.z, a1.w);
        ((uint*)&zv)[0] = cvt_pk(z0.x, z0.y);
        ((uint*)&zv)[1] = cvt_pk(z0.z, z0.w);
        ((uint*)&zv)[2] = cvt_pk(z1.x, z1.y);
        ((uint*)&zv)[3] = cvt_pk(z1.z, z1.w);
        *(short8*)((char*)xs + SWZ(row, c8 * 16)) = xv;
        *(short8*)((char*)zs + SWZ(row, c8 * 16)) = zv;
    }
    // stage pre-cast bf16 weights (no conversion)
#pragma unroll
    for (int c = 0; c < 2; ++c) {
        int chunk = c * 256 + t;
        int row   = chunk >> 3;
        int c8    = chunk & 7;
        short8 qv = *(const short8*)&Wqb[(size_t)h * 4096 + row * 64 + c8 * 8];
        short8 kv = *(const short8*)&Wkb[(size_t)h * 4096 + row * 64 + c8 * 8];
        short8 vv = *(const short8*)&Wvb[(size_t)h * 4096 + row * 64 + c8 * 8];
        *(short8*)((char*)wqs + SWZ(row, c8 * 16)) = qv;
        *(short8*)((char*)wks + SWZ(row, c8 * 16)) = kv;
        *(short8*)((char*)wvs + SWZ(row, c8 * 16)) = vv;
    }
    __syncthreads();

    floatx4 aq[2][4], ak[2][4], av[2][4];
#pragma unroll
    for (int i = 0; i < 2; ++i)
#pragma unroll
        for (int j = 0; j < 4; ++j) {
            aq[i][j] = (floatx4){0.f, 0.f, 0.f, 0.f};
            ak[i][j] = (floatx4){0.f, 0.f, 0.f, 0.f};
            av[i][j] = (floatx4){0.f, 0.f, 0.f, 0.f};
        }

#pragma unroll
    for (int kc = 0; kc < 2; ++kc) {
        short8 xa[2], za[2];
#pragma unroll
        for (int i = 0; i < 2; ++i) {
            int row = w * 32 + i * 16 + l16;
            xa[i] = *(const short8*)((const char*)xs + SWZ(row, kc * 64 + lg * 16));
            za[i] = *(const short8*)((const char*)zs + SWZ(row, kc * 64 + lg * 16));
        }
#pragma unroll
        for (int j = 0; j < 4; ++j) {
            int row = j * 16 + l16;
            short8 wqf = *(const short8*)((const char*)wqs + SWZ(row, kc * 64 + lg * 16));
            short8 wkf = *(const short8*)((const char*)wks + SWZ(row, kc * 64 + lg * 16));
            short8 wvf = *(const short8*)((const char*)wvs + SWZ(row, kc * 64 + lg * 16));
#pragma unroll
            for (int i = 0; i < 2; ++i) {
                aq[i][j] = __builtin_amdgcn_mfma_f32_16x16x32_bf16(xa[i], wqf, aq[i][j], 0, 0, 0);
                ak[i][j] = __builtin_amdgcn_mfma_f32_16x16x32_bf16(za[i], wkf, ak[i][j], 0, 0, 0);
                av[i][j] = __builtin_amdgcn_mfma_f32_16x16x32_bf16(za[i], wvf, av[i][j], 0, 0, 0);
            }
        }
    }

    float bqv[4], bkv[4], bvv[4];
#pragma unroll
    for (int j = 0; j < 4; ++j) {
        bqv[j] = bq[h * 64 + j * 16 + l16];
        bkv[j] = bk[h * 64 + j * 16 + l16];
        bvv[j] = bv[h * 64 + j * 16 + l16];
    }

#pragma unroll
    for (int i = 0; i < 2; ++i)
#pragma unroll
        for (int j = 0; j < 4; ++j) {
            int d = j * 16 + l16;
            int s = s0 + w * 32 + i * 16 + lg * 4;
            uint2 pv2;
            pv2.x = cvt_pk(av[i][j][0] + bvv[j], av[i][j][1] + bvv[j]);
            pv2.y = cvt_pk(av[i][j][2] + bvv[j], av[i][j][3] + bvv[j]);
            *(uint2*)&Vt[((size_t)bh * NHD + d) * NS + s] = pv2;
        }

    __syncthreads();
#pragma unroll
    for (int i = 0; i < 2; ++i)
#pragma unroll
        for (int j = 0; j < 4; ++j)
#pragma unroll
            for (int r = 0; r < 4; r += 2) {
                int sA = w * 32 + i * 16 + lg * 4 + r;
                uint uq = cvt_pk(aq[i][j][r] + bqv[j], aq[i][j][r + 1] + bqv[j]);
                uint uk = cvt_pk(ak[i][j][r] + bkv[j], ak[i][j][r + 1] + bkv[j]);
                xs[sA * 72 + j * 16 + l16]       = (ushort)uq;
                xs[(sA + 1) * 72 + j * 16 + l16] = (ushort)(uq >> 16);
                zs[sA * 72 + j * 16 + l16]       = (ushort)uk;
                zs[(sA + 1) * 72 + j * 16 + l16] = (ushort)(uk >> 16);
            }
    __syncthreads();
#pragma unroll
    for (int c = 0; c < 4; ++c) {
        int chunk = c * 256 + t;
        int row   = chunk >> 3;
        int c8    = chunk & 7;
        short8 qv = *(const short8*)&xs[row * 72 + c8 * 8];
        short8 kv = *(const short8*)&zs[row * 72 + c8 * 8];
        *(short8*)&Q[((size_t)bh * NS + s0 + row) * 64 + c8 * 8] = qv;
        *(short8*)&K[((size_t)bh * NS + s0 + row) * 64 + c8 * 8] = kv;
    }
}

// ---------------------------------------------------------------------------
// Kernel 2: MFMA flash attention — R15 proven structure restored verbatim
// (8 waves, 128 q rows, shared K/V tile, reg-staged dbuf, 1 barrier/epoch,
// cvt_pk, complementary-tq placement, EAGER ln reduce [R17: deferring it
// regressed 8% — the shuffle chain covers the prefetch drain]).
// ---------------------------------------------------------------------------
__global__ __launch_bounds__(512) void flash_attn(
    const ushort* __restrict__ Q, const ushort* __restrict__ K,
    const ushort* __restrict__ Vt, ushort* __restrict__ A)
{
    int bh = blockIdx.y;
    // complementary pairing: (x, bh) and (x, bh+16) sum to gridDim.x-1
    int tq = (bh < NH) ? ((gridDim.x - 1) - blockIdx.x) : blockIdx.x;
    int h = bh & (NH - 1), b = bh >> 4;

    __shared__ __align__(16) ushort k_lds[2][64 * 64];
    __shared__ __align__(16) ushort v_lds[2][64 * 64];
    __shared__ __align__(16) ushort p_lds[8][16 * 72];

    int t = threadIdx.x, w = t >> 6, l = t & 63;
    int l16 = l & 15, lg = l >> 4;
    int w4 = w & 3, wh = w >> 2;

    const ushort* Qb = Q + (size_t)bh * NS * NHD;
    const ushort* Kb = K + (size_t)bh * NS * NHD;
    const ushort* Vb = Vt + (size_t)bh * NHD * NS;

    int q0 = tq * 128;
    const float QSCALE = 0.125f * 1.44269504088896f;

    short8 qf[2];
#pragma unroll
    for (int c = 0; c < 2; ++c) {
        short8 raw = *(const short8*)&Qb[(size_t)(q0 + w * 16 + l16) * 64 + c * 32 + lg * 8];
#pragma unroll
        for (int j = 0; j < 4; ++j)
            ((uint*)&qf[c])[j] = cvt_pk(bf2f(((ushort*)&raw)[2 * j]) * QSCALE,
                                        bf2f(((ushort*)&raw)[2 * j + 1]) * QSCALE);
    }

    floatx4 ob[4];
#pragma unroll
    for (int d = 0; d < 4; ++d) ob[d] = (floatx4){0.f, 0.f, 0.f, 0.f};
    float m = -1e30f, ln = 0.f;

    // block-wide staging: 512 threads x 16B = one 64x64 bf16 tile each for K,V
    int rrow = t >> 3, rcb = (t & 7) * 8;

    short8 kpre, vpre;
    kpre = *(const short8*)&Kb[(size_t)rrow * 64 + rcb];
    vpre = *(const short8*)&Vb[(size_t)rrow * NS + rcb];
    *(short8*)((char*)k_lds[0] + SWZ(rrow, rcb * 2)) = kpre;
    *(short8*)((char*)v_lds[0] + SWZ(rrow, rcb * 2)) = vpre;

    int nt  = 2 * tq + 2;          // kv tiles 0 .. 2tq+1
    int lim = 2 * tq + wh;         // this wave's last (diagonal) tile

    for (int it = 0; it < nt; ++it) {
        __syncthreads();           // buf[it&1] ready; prior reads of buf[nxt] done
        int cur = it & 1, nxt = cur ^ 1;
        bool have_next = (it + 1 < nt);
        if (have_next) {           // issue loads early (hide under compute)
            kpre = *(const short8*)&Kb[(size_t)((it + 1) * 64 + rrow) * 64 + rcb];
            vpre = *(const short8*)&Vb[(size_t)rrow * NS + (it + 1) * 64 + rcb];
        }

        if (it <= lim) {
            // ---- S^T: sv[stt][r] = S[k=stt*16+lg*4+r][q=l16] (log2 dom.)
            floatx4 sv[4];
#pragma unroll
            for (int stt = 0; stt < 4; ++stt) {
                floatx4 acc = {0.f, 0.f, 0.f, 0.f};
#pragma unroll
                for (int c = 0; c < 2; ++c) {
                    int row = stt * 16 + l16;
                    short8 kf = *(const short8*)((const char*)k_lds[cur] +
                                                 SWZ(row, c * 64 + lg * 16));
                    acc = __builtin_amdgcn_mfma_f32_16x16x32_bf16(kf, qf[c], acc, 0, 0, 0);
                }
                sv[stt] = acc;
            }
            if (it == lim) {       // diagonal tile for this wave
#pragma unroll
                for (int stt = 0; stt < 4; ++stt)
#pragma unroll
                    for (int r = 0; r < 4; ++r)
                        if (stt * 16 + lg * 4 + r > w4 * 16 + l16) sv[stt][r] = -1e30f;
            }

            // ---- softmax: in-register 16-max + 2 shuffles ----
            float p01 = fmaxf(fmaxf(sv[0][0], sv[0][1]), fmaxf(sv[0][2], sv[0][3]));
            float p23 = fmaxf(fmaxf(sv[1][0], sv[1][1]), fmaxf(sv[1][2], sv[1][3]));
            float p45 = fmaxf(fmaxf(sv[2][0], sv[2][1]), fmaxf(sv[2][2], sv[2][3]));
            float p67 = fmaxf(fmaxf(sv[3][0], sv[3][1]), fmaxf(sv[3][2], sv[3][3]));
            float pmax = fmaxf(fmaxf(p01, p23), fmaxf(p45, p67));
            pmax = fmaxf(pmax, __shfl_xor(pmax, 16, 64));
            pmax = fmaxf(pmax, __shfl_xor(pmax, 32, 64));

            if (!__all(pmax - m <= 8.0f)) {   // T13 defer-max (log2 units)
                float mn = fmaxf(m, pmax);
                float al = exp2f(m - mn);
                m = mn;
                ln *= al;
#pragma unroll
                for (int d = 0; d < 4; ++d)
#pragma unroll
                    for (int r = 0; r < 4; ++r) ob[d][r] *= al;
            }

            float rs = 0.f;
#pragma unroll
            for (int stt = 0; stt < 4; ++stt)
#pragma unroll
                for (int r = 0; r < 4; ++r) {
                    float p = exp2f(sv[stt][r] - m);
                    sv[stt][r] = p;
                    rs += p;
                }
            rs += __shfl_xor(rs, 16, 64);
            rs += __shfl_xor(rs, 32, 64);
            ln += rs;

            // ---- P -> p_lds[q][k] via packed cvt, then PV: O^T = V^T P ----
#pragma unroll
            for (int stt = 0; stt < 4; ++stt) {
                uint2 pk2;
                pk2.x = cvt_pk(sv[stt][0], sv[stt][1]);
                pk2.y = cvt_pk(sv[stt][2], sv[stt][3]);
                *(uint2*)&p_lds[w][l16 * 72 + stt * 16 + lg * 4] = pk2;
            }

#pragma unroll
            for (int ks = 0; ks < 2; ++ks) {
                short8 pf = *(const short8*)((const char*)&p_lds[w][0] +
                                             (l16 * 144 + ks * 64 + lg * 16));
#pragma unroll
                for (int d = 0; d < 4; ++d) {
                    int vrow = d * 16 + l16;
                    short8 vf = *(const short8*)((const char*)v_lds[cur] +
                                                 SWZ(vrow, ks * 64 + lg * 16));
                    ob[d] = __builtin_amdgcn_mfma_f32_16x16x32_bf16(vf, pf, ob[d], 0, 0, 0);
                }
            }
        }

        if (have_next) {           // write prefetched tile into the other buffer
            *(short8*)((char*)k_lds[nxt] + SWZ(rrow, rcb * 2)) = kpre;
            *(short8*)((char*)v_lds[nxt] + SWZ(rrow, rcb * 2)) = vpre;
        }
    }

    // epilogue: lane owns q = q0 + w*16 + l16; d = d0*16 + lg*4 + r
    float inv = 1.0f / ln;
    int qq = q0 + w * 16 + l16;
#pragma unroll
    for (int d = 0; d < 4; ++d) {
        uint2 ov;
        ov.x = cvt_pk(ob[d][0] * inv, ob[d][1] * inv);
        ov.y = cvt_pk(ob[d][2] * inv, ob[d][3] * inv);
        *(uint2*)&A[(size_t)(b * NS + qq) * NEMB + h * 64 + d * 16 + lg * 4] = ov;
    }
}

// ---------------------------------------------------------------------------
// Kernel 3: Y = A @ Wo^T + bo via bf16 MFMA, fp32 accum.
// 64x128 tile, grid (64,8) = 512 blocks = 2/CU. Staging via global_load_lds
// (w=16): linear LDS dest (wave-uniform base + lane*16), source byte-col
// pre-swizzled ((l&7)^(l>>3))*16 so the image equals the SWZ layout (rule 21;
// pattern correctness-verified in R16). Barrier-synced drain = m97 structure.
// ---------------------------------------------------------------------------
__global__ __launch_bounds__(256) void out_gemm_mfma(
    const ushort* __restrict__ Aq, const ushort* __restrict__ Wob,
    const float* __restrict__ bo, float* __restrict__ Y)
{
    int m0 = blockIdx.x * 64;
    int n0 = blockIdx.y * 128;

    __shared__ __align__(16) ushort As[64 * 64];    // [m][k], swizzled image
    __shared__ __align__(16) ushort Bs[128 * 64];   // [n][k], swizzled image

    int t = threadIdx.x, w = t >> 6, l = t & 63;
    int l16 = l & 15, lg = l >> 4;
    int wr = w >> 1, wc = w & 1;    // wave tile: rows wr*32, cols wc*64

    // gload staging geometry: lane l covers row-offset (l>>3), chunk (l&7);
    // source col pre-swizzled so linear dest reproduces SWZ image.
    int lr   = l >> 3;
    int colb = ((l & 7) ^ lr) * 16;                 // source byte-col
    const char* Asrc = (const char*)Aq  + (size_t)m0 * 2048;
    const char* Bsrc = (const char*)Wob + (size_t)n0 * 2048;

    floatx4 acc[2][4];
#pragma unroll
    for (int i = 0; i < 2; ++i)
#pragma unroll
        for (int j = 0; j < 4; ++j) acc[i][j] = (floatx4){0.f, 0.f, 0.f, 0.f};

    for (int kt = 0; kt < 16; ++kt) {
        __syncthreads();            // prior compute's LDS reads done
#pragma unroll
        for (int p = 0; p < 2; ++p) {     // As: 64 rows (4 waves x 2 x 8 rows)
            int rbase = p * 32 + w * 8;
            gload16(Asrc + (size_t)(rbase + lr) * 2048 + kt * 128 + colb,
                    (char*)As + rbase * 128);
        }
#pragma unroll
        for (int p = 0; p < 4; ++p) {     // Bs: 128 rows
            int rbase = p * 32 + w * 8;
            gload16(Bsrc + (size_t)(rbase + lr) * 2048 + kt * 128 + colb,
                    (char*)Bs + rbase * 128);
        }
        __syncthreads();            // compiler drains vmcnt before barrier
#pragma unroll
        for (int kc = 0; kc < 2; ++kc) {
            short8 af[2], bf[4];
#pragma unroll
            for (int i = 0; i < 2; ++i) {
                int arow = wr * 32 + i * 16 + l16;
                af[i] = *(const short8*)((const char*)As + SWZ(arow, kc * 64 + lg * 16));
            }
#pragma unroll
            for (int j = 0; j < 4; ++j) {
                int brow = wc * 64 + j * 16 + l16;
                bf[j] = *(const short8*)((const char*)Bs + SWZ(brow, kc * 64 + lg * 16));
            }
#pragma unroll
            for (int i = 0; i < 2; ++i)
#pragma unroll
                for (int j = 0; j < 4; ++j)
                    acc[i][j] = __builtin_amdgcn_mfma_f32_16x16x32_bf16(
                        af[i], bf[j], acc[i][j], 0, 0, 0);
        }
    }
#pragma unroll
    for (int i = 0; i < 2; ++i)
#pragma unroll
        for (int j = 0; j < 4; ++j) {
            int nn = n0 + wc * 64 + j * 16 + l16;
            float bb = bo[nn];
#pragma unroll
            for (int r = 0; r < 4; ++r) {
                int mm = m0 + wr * 32 + i * 16 + lg * 4 + r;
                Y[(size_t)mm * 1024 + nn] = acc[i][j][r] + bb;
            }
        }
}

// ---------------------------------------------------------------------------
extern "C" void kernel_launch(void* const* d_in, const int* in_sizes, int n_in,
                              void* d_out, int out_size, void* d_ws, size_t ws_size,
                              hipStream_t stream) {
    const float* X  = (const float*)d_in[0];
    const float* Z  = (const float*)d_in[1];
    const float* Wq = (const float*)d_in[2];
    const float* bq = (const float*)d_in[3];
    const float* Wk = (const float*)d_in[4];
    const float* bk = (const float*)d_in[5];
    const float* Wv = (const float*)d_in[6];
    const float* bv = (const float*)d_in[7];
    const float* Wo = (const float*)d_in[8];
    const float* bo = (const float*)d_in[9];
    float* out = (float*)d_out;

    const size_t NQ = (size_t)NB * NH * NS * NHD;   // 4M elems
    ushort* Qd  = (ushort*)d_ws;
    ushort* Kd  = Qd + NQ;
    ushort* Vtd = Kd + NQ;
    ushort* Ad  = Vtd + NQ;
    ushort* Wqb = Ad + NQ;                          // 65536 elems
    ushort* Wkb = Wqb + 65536;
    ushort* Wvb = Wkb + 65536;
    ushort* Wob = Wvb + 65536;                      // 1M elems

    w_cast<<<dim3(608), 256, 0, stream>>>(Wq, Wk, Wv, Wo, Wqb, Wkb, Wvb, Wob);
    qkv_mfma<<<dim3(NS / 128, NB * NH), 256, 0, stream>>>(
        X, Z, Wqb, bq, Wkb, bk, Wvb, bv, Qd, Kd, Vtd);
    flash_attn<<<dim3(NS / 128, NB * NH), 512, 0, stream>>>(Qd, Kd, Vtd, Ad);
    out_gemm_mfma<<<dim3(64, 8), 256, 0, stream>>>(Ad, Wob, bo, out);
}

// Round 20
// 80.510 us; speedup vs baseline: 1.2016x; 1.0330x over previous
//
#include <hip/hip_runtime.h>
#include <hip/hip_bf16.h>
#include <math.h>

#define NB   2
#define NS   2048
#define NEMB 1024
#define NH   16
#define NHD  64

typedef __attribute__((ext_vector_type(8))) short short8;
typedef __attribute__((ext_vector_type(4))) float floatx4;

static __device__ __forceinline__ float bf2f(ushort u) {
    union { uint u; float f; } x; x.u = ((uint)u) << 16;
    return x.f;
}
// HW packed convert: dword = [bf16(lo) | bf16(hi)<<16]
static __device__ __forceinline__ uint cvt_pk(float lo, float hi) {
    uint r;
    asm("v_cvt_pk_bf16_f32 %0, %1, %2" : "=v"(r) : "v"(lo), "v"(hi));
    return r;
}
// async global->LDS, 16B/lane; LDS dest = wave-uniform base + lane*16
static __device__ __forceinline__ void gload16(const void* g, void* s) {
    __builtin_amdgcn_global_load_lds(
        (const __attribute__((address_space(1))) void*)g,
        (__attribute__((address_space(3))) void*)s, 16, 0, 0);
}

#define SWZ(row, bytecol) (((row) * 128 + (bytecol)) ^ (((row) & 7) << 4))

// ---------------------------------------------------------------------------
// Kernel 1: fused QKV projection via MFMA + concurrent Wo cast.
// grid = (16, 34), block 256.
//   y < 32 : QKV for bh=y, s-tile x (weights staged from fp32, inline cvt_pk)
//   y >= 32: Wo fp32->bf16 cast slice ((y-32)*16+x of 32 slices x 32768 elems
//            = 1048576 total — FULL coverage [R19 bug: 8 iters covered half]).
// ---------------------------------------------------------------------------
__global__ __launch_bounds__(256) void qkv_mfma(
    const float* __restrict__ X, const float* __restrict__ Z,
    const float* __restrict__ Wq, const float* __restrict__ bq,
    const float* __restrict__ Wk, const float* __restrict__ bk,
    const float* __restrict__ Wv, const float* __restrict__ bv,
    const float* __restrict__ Wo, ushort* __restrict__ Wob,
    ushort* __restrict__ Q, ushort* __restrict__ K, ushort* __restrict__ Vt)
{
    int st = blockIdx.x, bh = blockIdx.y;
    int t = threadIdx.x;

    if (bh >= 32) {                       // ---- Wo cast path ----
        int slice = (bh - 32) * 16 + st;  // 0..31
        int base  = slice * 32768;        // 32 x 32768 = 1048576 = |Wo|
#pragma unroll
        for (int it2 = 0; it2 < 16; ++it2) {
            int i = base + it2 * 2048 + t * 8;
            float4 a = *(const float4*)&Wo[i];
            float4 c = *(const float4*)&Wo[i + 4];
            short8 o;
            ((uint*)&o)[0] = cvt_pk(a.x, a.y);
            ((uint*)&o)[1] = cvt_pk(a.z, a.w);
            ((uint*)&o)[2] = cvt_pk(c.x, c.y);
            ((uint*)&o)[3] = cvt_pk(c.z, c.w);
            *(short8*)&Wob[i] = o;
        }
        return;
    }

    int h = bh & (NH - 1), b = bh >> 4;
    int s0 = st * 128;

    __shared__ __align__(16) ushort xs[128 * 72];
    __shared__ __align__(16) ushort zs[128 * 72];
    __shared__ __align__(16) ushort wqs[64 * 64], wks[64 * 64], wvs[64 * 64];

    int w = t >> 6, l = t & 63;
    int l16 = l & 15, lg = l >> 4;

#pragma unroll
    for (int c = 0; c < 4; ++c) {
        int chunk = c * 256 + t;
        int row   = chunk >> 3;
        int c8    = chunk & 7;
        const float* px = &X[(size_t)(b * NS + s0 + row) * NEMB + h * 64 + c8 * 8];
        const float* pz = &Z[(size_t)(b * NS + s0 + row) * NEMB + h * 64 + c8 * 8];
        float4 a0 = *(const float4*)px, a1 = *(const float4*)(px + 4);
        float4 z0 = *(const float4*)pz, z1 = *(const float4*)(pz + 4);
        short8 xv, zv;
        ((uint*)&xv)[0] = cvt_pk(a0.x, a0.y);
        ((uint*)&xv)[1] = cvt_pk(a0.z, a0.w);
        ((uint*)&xv)[2] = cvt_pk(a1.x, a1.y);
        ((uint*)&xv)[3] = cvt_pk(a1.z, a1.w);
        ((uint*)&zv)[0] = cvt_pk(z0.x, z0.y);
        ((uint*)&zv)[1] = cvt_pk(z0.z, z0.w);
        ((uint*)&zv)[2] = cvt_pk(z1.x, z1.y);
        ((uint*)&zv)[3] = cvt_pk(z1.z, z1.w);
        *(short8*)((char*)xs + SWZ(row, c8 * 16)) = xv;
        *(short8*)((char*)zs + SWZ(row, c8 * 16)) = zv;
    }
    // stage Wq/Wk/Wv for this head from fp32 (inline cvt_pk)
#pragma unroll
    for (int c = 0; c < 2; ++c) {
        int chunk = c * 256 + t;
        int row   = chunk >> 3;
        int c8    = chunk & 7;
        const float* pq = &Wq[(size_t)h * 4096 + row * 64 + c8 * 8];
        const float* pk = &Wk[(size_t)h * 4096 + row * 64 + c8 * 8];
        const float* pv = &Wv[(size_t)h * 4096 + row * 64 + c8 * 8];
        float4 q0 = *(const float4*)pq, q1 = *(const float4*)(pq + 4);
        float4 k0 = *(const float4*)pk, k1 = *(const float4*)(pk + 4);
        float4 v0 = *(const float4*)pv, v1 = *(const float4*)(pv + 4);
        short8 qv, kv, vv;
        ((uint*)&qv)[0] = cvt_pk(q0.x, q0.y); ((uint*)&qv)[1] = cvt_pk(q0.z, q0.w);
        ((uint*)&qv)[2] = cvt_pk(q1.x, q1.y); ((uint*)&qv)[3] = cvt_pk(q1.z, q1.w);
        ((uint*)&kv)[0] = cvt_pk(k0.x, k0.y); ((uint*)&kv)[1] = cvt_pk(k0.z, k0.w);
        ((uint*)&kv)[2] = cvt_pk(k1.x, k1.y); ((uint*)&kv)[3] = cvt_pk(k1.z, k1.w);
        ((uint*)&vv)[0] = cvt_pk(v0.x, v0.y); ((uint*)&vv)[1] = cvt_pk(v0.z, v0.w);
        ((uint*)&vv)[2] = cvt_pk(v1.x, v1.y); ((uint*)&vv)[3] = cvt_pk(v1.z, v1.w);
        *(short8*)((char*)wqs + SWZ(row, c8 * 16)) = qv;
        *(short8*)((char*)wks + SWZ(row, c8 * 16)) = kv;
        *(short8*)((char*)wvs + SWZ(row, c8 * 16)) = vv;
    }
    __syncthreads();

    floatx4 aq[2][4], ak[2][4], av[2][4];
#pragma unroll
    for (int i = 0; i < 2; ++i)
#pragma unroll
        for (int j = 0; j < 4; ++j) {
            aq[i][j] = (floatx4){0.f, 0.f, 0.f, 0.f};
            ak[i][j] = (floatx4){0.f, 0.f, 0.f, 0.f};
            av[i][j] = (floatx4){0.f, 0.f, 0.f, 0.f};
        }

#pragma unroll
    for (int kc = 0; kc < 2; ++kc) {
        short8 xa[2], za[2];
#pragma unroll
        for (int i = 0; i < 2; ++i) {
            int row = w * 32 + i * 16 + l16;
            xa[i] = *(const short8*)((const char*)xs + SWZ(row, kc * 64 + lg * 16));
            za[i] = *(const short8*)((const char*)zs + SWZ(row, kc * 64 + lg * 16));
        }
#pragma unroll
        for (int j = 0; j < 4; ++j) {
            int row = j * 16 + l16;
            short8 wqf = *(const short8*)((const char*)wqs + SWZ(row, kc * 64 + lg * 16));
            short8 wkf = *(const short8*)((const char*)wks + SWZ(row, kc * 64 + lg * 16));
            short8 wvf = *(const short8*)((const char*)wvs + SWZ(row, kc * 64 + lg * 16));
#pragma unroll
            for (int i = 0; i < 2; ++i) {
                aq[i][j] = __builtin_amdgcn_mfma_f32_16x16x32_bf16(xa[i], wqf, aq[i][j], 0, 0, 0);
                ak[i][j] = __builtin_amdgcn_mfma_f32_16x16x32_bf16(za[i], wkf, ak[i][j], 0, 0, 0);
                av[i][j] = __builtin_amdgcn_mfma_f32_16x16x32_bf16(za[i], wvf, av[i][j], 0, 0, 0);
            }
        }
    }

    float bqv[4], bkv[4], bvv[4];
#pragma unroll
    for (int j = 0; j < 4; ++j) {
        bqv[j] = bq[h * 64 + j * 16 + l16];
        bkv[j] = bk[h * 64 + j * 16 + l16];
        bvv[j] = bv[h * 64 + j * 16 + l16];
    }

#pragma unroll
    for (int i = 0; i < 2; ++i)
#pragma unroll
        for (int j = 0; j < 4; ++j) {
            int d = j * 16 + l16;
            int s = s0 + w * 32 + i * 16 + lg * 4;
            uint2 pv2;
            pv2.x = cvt_pk(av[i][j][0] + bvv[j], av[i][j][1] + bvv[j]);
            pv2.y = cvt_pk(av[i][j][2] + bvv[j], av[i][j][3] + bvv[j]);
            *(uint2*)&Vt[((size_t)bh * NHD + d) * NS + s] = pv2;
        }

    __syncthreads();
#pragma unroll
    for (int i = 0; i < 2; ++i)
#pragma unroll
        for (int j = 0; j < 4; ++j)
#pragma unroll
            for (int r = 0; r < 4; r += 2) {
                int sA = w * 32 + i * 16 + lg * 4 + r;
                uint uq = cvt_pk(aq[i][j][r] + bqv[j], aq[i][j][r + 1] + bqv[j]);
                uint uk = cvt_pk(ak[i][j][r] + bkv[j], ak[i][j][r + 1] + bkv[j]);
                xs[sA * 72 + j * 16 + l16]       = (ushort)uq;
                xs[(sA + 1) * 72 + j * 16 + l16] = (ushort)(uq >> 16);
                zs[sA * 72 + j * 16 + l16]       = (ushort)uk;
                zs[(sA + 1) * 72 + j * 16 + l16] = (ushort)(uk >> 16);
            }
    __syncthreads();
#pragma unroll
    for (int c = 0; c < 4; ++c) {
        int chunk = c * 256 + t;
        int row   = chunk >> 3;
        int c8    = chunk & 7;
        short8 qv = *(const short8*)&xs[row * 72 + c8 * 8];
        short8 kv = *(const short8*)&zs[row * 72 + c8 * 8];
        *(short8*)&Q[((size_t)bh * NS + s0 + row) * 64 + c8 * 8] = qv;
        *(short8*)&K[((size_t)bh * NS + s0 + row) * 64 + c8 * 8] = kv;
    }
}

// ---------------------------------------------------------------------------
// Kernel 2: MFMA flash attention — proven R15/R18 structure, unchanged.
// ---------------------------------------------------------------------------
__global__ __launch_bounds__(512) void flash_attn(
    const ushort* __restrict__ Q, const ushort* __restrict__ K,
    const ushort* __restrict__ Vt, ushort* __restrict__ A)
{
    int bh = blockIdx.y;
    // complementary pairing: (x, bh) and (x, bh+16) sum to gridDim.x-1
    int tq = (bh < NH) ? ((gridDim.x - 1) - blockIdx.x) : blockIdx.x;
    int h = bh & (NH - 1), b = bh >> 4;

    __shared__ __align__(16) ushort k_lds[2][64 * 64];
    __shared__ __align__(16) ushort v_lds[2][64 * 64];
    __shared__ __align__(16) ushort p_lds[8][16 * 72];

    int t = threadIdx.x, w = t >> 6, l = t & 63;
    int l16 = l & 15, lg = l >> 4;
    int w4 = w & 3, wh = w >> 2;

    const ushort* Qb = Q + (size_t)bh * NS * NHD;
    const ushort* Kb = K + (size_t)bh * NS * NHD;
    const ushort* Vb = Vt + (size_t)bh * NHD * NS;

    int q0 = tq * 128;
    const float QSCALE = 0.125f * 1.44269504088896f;

    short8 qf[2];
#pragma unroll
    for (int c = 0; c < 2; ++c) {
        short8 raw = *(const short8*)&Qb[(size_t)(q0 + w * 16 + l16) * 64 + c * 32 + lg * 8];
#pragma unroll
        for (int j = 0; j < 4; ++j)
            ((uint*)&qf[c])[j] = cvt_pk(bf2f(((ushort*)&raw)[2 * j]) * QSCALE,
                                        bf2f(((ushort*)&raw)[2 * j + 1]) * QSCALE);
    }

    floatx4 ob[4];
#pragma unroll
    for (int d = 0; d < 4; ++d) ob[d] = (floatx4){0.f, 0.f, 0.f, 0.f};
    float m = -1e30f, ln = 0.f;

    // block-wide staging: 512 threads x 16B = one 64x64 bf16 tile each for K,V
    int rrow = t >> 3, rcb = (t & 7) * 8;

    short8 kpre, vpre;
    kpre = *(const short8*)&Kb[(size_t)rrow * 64 + rcb];
    vpre = *(const short8*)&Vb[(size_t)rrow * NS + rcb];
    *(short8*)((char*)k_lds[0] + SWZ(rrow, rcb * 2)) = kpre;
    *(short8*)((char*)v_lds[0] + SWZ(rrow, rcb * 2)) = vpre;

    int nt  = 2 * tq + 2;          // kv tiles 0 .. 2tq+1
    int lim = 2 * tq + wh;         // this wave's last (diagonal) tile

    for (int it = 0; it < nt; ++it) {
        __syncthreads();           // buf[it&1] ready; prior reads of buf[nxt] done
        int cur = it & 1, nxt = cur ^ 1;
        bool have_next = (it + 1 < nt);
        if (have_next) {           // issue loads early (hide under compute)
            kpre = *(const short8*)&Kb[(size_t)((it + 1) * 64 + rrow) * 64 + rcb];
            vpre = *(const short8*)&Vb[(size_t)rrow * NS + (it + 1) * 64 + rcb];
        }

        if (it <= lim) {
            // ---- S^T: sv[stt][r] = S[k=stt*16+lg*4+r][q=l16] (log2 dom.)
            floatx4 sv[4];
#pragma unroll
            for (int stt = 0; stt < 4; ++stt) {
                floatx4 acc = {0.f, 0.f, 0.f, 0.f};
#pragma unroll
                for (int c = 0; c < 2; ++c) {
                    int row = stt * 16 + l16;
                    short8 kf = *(const short8*)((const char*)k_lds[cur] +
                                                 SWZ(row, c * 64 + lg * 16));
                    acc = __builtin_amdgcn_mfma_f32_16x16x32_bf16(kf, qf[c], acc, 0, 0, 0);
                }
                sv[stt] = acc;
            }
            if (it == lim) {       // diagonal tile for this wave
#pragma unroll
                for (int stt = 0; stt < 4; ++stt)
#pragma unroll
                    for (int r = 0; r < 4; ++r)
                        if (stt * 16 + lg * 4 + r > w4 * 16 + l16) sv[stt][r] = -1e30f;
            }

            // ---- softmax: in-register 16-max + 2 shuffles ----
            float p01 = fmaxf(fmaxf(sv[0][0], sv[0][1]), fmaxf(sv[0][2], sv[0][3]));
            float p23 = fmaxf(fmaxf(sv[1][0], sv[1][1]), fmaxf(sv[1][2], sv[1][3]));
            float p45 = fmaxf(fmaxf(sv[2][0], sv[2][1]), fmaxf(sv[2][2], sv[2][3]));
            float p67 = fmaxf(fmaxf(sv[3][0], sv[3][1]), fmaxf(sv[3][2], sv[3][3]));
            float pmax = fmaxf(fmaxf(p01, p23), fmaxf(p45, p67));
            pmax = fmaxf(pmax, __shfl_xor(pmax, 16, 64));
            pmax = fmaxf(pmax, __shfl_xor(pmax, 32, 64));

            if (!__all(pmax - m <= 8.0f)) {   // T13 defer-max (log2 units)
                float mn = fmaxf(m, pmax);
                float al = exp2f(m - mn);
                m = mn;
                ln *= al;
#pragma unroll
                for (int d = 0; d < 4; ++d)
#pragma unroll
                    for (int r = 0; r < 4; ++r) ob[d][r] *= al;
            }

            float rs = 0.f;
#pragma unroll
            for (int stt = 0; stt < 4; ++stt)
#pragma unroll
                for (int r = 0; r < 4; ++r) {
                    float p = exp2f(sv[stt][r] - m);
                    sv[stt][r] = p;
                    rs += p;
                }
            rs += __shfl_xor(rs, 16, 64);
            rs += __shfl_xor(rs, 32, 64);
            ln += rs;

            // ---- P -> p_lds[q][k] via packed cvt, then PV: O^T = V^T P ----
#pragma unroll
            for (int stt = 0; stt < 4; ++stt) {
                uint2 pk2;
                pk2.x = cvt_pk(sv[stt][0], sv[stt][1]);
                pk2.y = cvt_pk(sv[stt][2], sv[stt][3]);
                *(uint2*)&p_lds[w][l16 * 72 + stt * 16 + lg * 4] = pk2;
            }

#pragma unroll
            for (int ks = 0; ks < 2; ++ks) {
                short8 pf = *(const short8*)((const char*)&p_lds[w][0] +
                                             (l16 * 144 + ks * 64 + lg * 16));
#pragma unroll
                for (int d = 0; d < 4; ++d) {
                    int vrow = d * 16 + l16;
                    short8 vf = *(const short8*)((const char*)v_lds[cur] +
                                                 SWZ(vrow, ks * 64 + lg * 16));
                    ob[d] = __builtin_amdgcn_mfma_f32_16x16x32_bf16(vf, pf, ob[d], 0, 0, 0);
                }
            }
        }

        if (have_next) {           // write prefetched tile into the other buffer
            *(short8*)((char*)k_lds[nxt] + SWZ(rrow, rcb * 2)) = kpre;
            *(short8*)((char*)v_lds[nxt] + SWZ(rrow, rcb * 2)) = vpre;
        }
    }

    // epilogue: lane owns q = q0 + w*16 + l16; d = d0*16 + lg*4 + r
    float inv = 1.0f / ln;
    int qq = q0 + w * 16 + l16;
#pragma unroll
    for (int d = 0; d < 4; ++d) {
        uint2 ov;
        ov.x = cvt_pk(ob[d][0] * inv, ob[d][1] * inv);
        ov.y = cvt_pk(ob[d][2] * inv, ob[d][3] * inv);
        *(uint2*)&A[(size_t)(b * NS + qq) * NEMB + h * 64 + d * 16 + lg * 4] = ov;
    }
}

// ---------------------------------------------------------------------------
// Kernel 3: Y = A @ Wo^T + bo via bf16 MFMA, fp32 accum — proven R18
// gload_lds structure, unchanged.
// ---------------------------------------------------------------------------
__global__ __launch_bounds__(256) void out_gemm_mfma(
    const ushort* __restrict__ Aq, const ushort* __restrict__ Wob,
    const float* __restrict__ bo, float* __restrict__ Y)
{
    int m0 = blockIdx.x * 64;
    int n0 = blockIdx.y * 128;

    __shared__ __align__(16) ushort As[64 * 64];    // [m][k], swizzled image
    __shared__ __align__(16) ushort Bs[128 * 64];   // [n][k], swizzled image

    int t = threadIdx.x, w = t >> 6, l = t & 63;
    int l16 = l & 15, lg = l >> 4;
    int wr = w >> 1, wc = w & 1;    // wave tile: rows wr*32, cols wc*64

    int lr   = l >> 3;
    int colb = ((l & 7) ^ lr) * 16;                 // source byte-col (inv-swz)
    const char* Asrc = (const char*)Aq  + (size_t)m0 * 2048;
    const char* Bsrc = (const char*)Wob + (size_t)n0 * 2048;

    floatx4 acc[2][4];
#pragma unroll
    for (int i = 0; i < 2; ++i)
#pragma unroll
        for (int j = 0; j < 4; ++j) acc[i][j] = (floatx4){0.f, 0.f, 0.f, 0.f};

    for (int kt = 0; kt < 16; ++kt) {
        __syncthreads();            // prior compute's LDS reads done
#pragma unroll
        for (int p = 0; p < 2; ++p) {     // As: 64 rows
            int rbase = p * 32 + w * 8;
            gload16(Asrc + (size_t)(rbase + lr) * 2048 + kt * 128 + colb,
                    (char*)As + rbase * 128);
        }
#pragma unroll
        for (int p = 0; p < 4; ++p) {     // Bs: 128 rows
            int rbase = p * 32 + w * 8;
            gload16(Bsrc + (size_t)(rbase + lr) * 2048 + kt * 128 + colb,
                    (char*)Bs + rbase * 128);
        }
        __syncthreads();            // compiler drains vmcnt before barrier
#pragma unroll
        for (int kc = 0; kc < 2; ++kc) {
            short8 af[2], bf[4];
#pragma unroll
            for (int i = 0; i < 2; ++i) {
                int arow = wr * 32 + i * 16 + l16;
                af[i] = *(const short8*)((const char*)As + SWZ(arow, kc * 64 + lg * 16));
            }
#pragma unroll
            for (int j = 0; j < 4; ++j) {
                int brow = wc * 64 + j * 16 + l16;
                bf[j] = *(const short8*)((const char*)Bs + SWZ(brow, kc * 64 + lg * 16));
            }
#pragma unroll
            for (int i = 0; i < 2; ++i)
#pragma unroll
                for (int j = 0; j < 4; ++j)
                    acc[i][j] = __builtin_amdgcn_mfma_f32_16x16x32_bf16(
                        af[i], bf[j], acc[i][j], 0, 0, 0);
        }
    }
#pragma unroll
    for (int i = 0; i < 2; ++i)
#pragma unroll
        for (int j = 0; j < 4; ++j) {
            int nn = n0 + wc * 64 + j * 16 + l16;
            float bb = bo[nn];
#pragma unroll
            for (int r = 0; r < 4; ++r) {
                int mm = m0 + wr * 32 + i * 16 + lg * 4 + r;
                Y[(size_t)mm * 1024 + nn] = acc[i][j][r] + bb;
            }
        }
}

// ---------------------------------------------------------------------------
extern "C" void kernel_launch(void* const* d_in, const int* in_sizes, int n_in,
                              void* d_out, int out_size, void* d_ws, size_t ws_size,
                              hipStream_t stream) {
    const float* X  = (const float*)d_in[0];
    const float* Z  = (const float*)d_in[1];
    const float* Wq = (const float*)d_in[2];
    const float* bq = (const float*)d_in[3];
    const float* Wk = (const float*)d_in[4];
    const float* bk = (const float*)d_in[5];
    const float* Wv = (const float*)d_in[6];
    const float* bv = (const float*)d_in[7];
    const float* Wo = (const float*)d_in[8];
    const float* bo = (const float*)d_in[9];
    float* out = (float*)d_out;

    const size_t NQ = (size_t)NB * NH * NS * NHD;   // 4M elems
    ushort* Qd  = (ushort*)d_ws;
    ushort* Kd  = Qd + NQ;
    ushort* Vtd = Kd + NQ;
    ushort* Ad  = Vtd + NQ;
    ushort* Wob = Ad + NQ;                          // 1M elems

    qkv_mfma<<<dim3(16, 34), 256, 0, stream>>>(
        X, Z, Wq, bq, Wk, bk, Wv, bv, Wo, Wob, Qd, Kd, Vtd);
    flash_attn<<<dim3(NS / 128, NB * NH), 512, 0, stream>>>(Qd, Kd, Vtd, Ad);
    out_gemm_mfma<<<dim3(64, 8), 256, 0, stream>>>(Ad, Wob, bo, out);
}